// Round 2
// baseline (9378.951 us; speedup 1.0000x reference)
//
#include <hip/hip_runtime.h>
#include <stdint.h>
#include <stddef.h>

// mRNN persistent kernel for MI355X (gfx950).
// B=64, T=512, I=128, N=2048.
// Strategy: one persistent kernel, 256 WGs (1 per CU, LDS-bound), W_eff held in
// LDS as bf16 for all 512 steps; rates broadcast via global double buffer;
// custom grid barrier (monotonic counter, agent-scope atomics).

#define B_   64
#define T_   512
#define I_   128
#define N_   2048
#define NWG  256
#define NTHR 256
#define ROWS 16   // b-rows per WG
#define COLS 32   // n-cols per WG
#define WPAD 8    // pad elems on W rows: stride 4112B -> conflict-free b128 frag reads
#define IPAD 8    // pad elems on Winp rows: stride 272B

typedef __bf16 bf16x8 __attribute__((ext_vector_type(8)));
typedef float  f32x4  __attribute__((ext_vector_type(4)));

__device__ __forceinline__ unsigned short f2bf_rn(float f) {
  unsigned int u = __float_as_uint(f);
  u += 0x7fffu + ((u >> 16) & 1u);          // round-to-nearest-even
  return (unsigned short)(u >> 16);
}
__device__ __forceinline__ float bf2f(unsigned short h) {
  return __uint_as_float(((unsigned int)h) << 16);
}

__device__ __forceinline__ f32x4 mfma16(bf16x8 a, bf16x8 b, f32x4 c) {
  return __builtin_amdgcn_mfma_f32_16x16x32_bf16(a, b, c, 0, 0, 0);
}

// x -> hi/lo bf16 split (Markidis) so drive GEMM is ~fp32-exact at MFMA speed.
__global__ void k_conv_x(const float* __restrict__ x,
                         unsigned short* __restrict__ xhi,
                         unsigned short* __restrict__ xlo, int n) {
  int i = blockIdx.x * blockDim.x + threadIdx.x;
  if (i < n) {
    float v = x[i];
    unsigned short h = f2bf_rn(v);
    xhi[i] = h;
    xlo[i] = f2bf_rn(v - bf2f(h));
  }
}

// Grid barrier: monotonic counter (no reset races). 1 WG/CU guarantees
// co-residency of all 256 WGs. Release on the add publishes wave0's global
// stores (r, out); acquire fence after the spin invalidates L1/L2 so the next
// step's cross-XCD r reads are fresh.
__device__ __forceinline__ void gridbar(int* cnt, int target) {
  __syncthreads();                       // drains each wave's vmcnt before publish
  if (threadIdx.x == 0) {
    __hip_atomic_fetch_add(cnt, 1, __ATOMIC_RELEASE, __HIP_MEMORY_SCOPE_AGENT);
    while (__hip_atomic_load(cnt, __ATOMIC_RELAXED, __HIP_MEMORY_SCOPE_AGENT) < target) {
      __builtin_amdgcn_s_sleep(1);
    }
  }
  __syncthreads();
  __builtin_amdgcn_fence(__ATOMIC_ACQUIRE, "agent");
}

__global__ __launch_bounds__(NTHR, 1) void rnn_persist(
    const float* __restrict__ h0,      // [64][2048]
    const float* __restrict__ Wrec,    // [2048][2048]
    const float* __restrict__ Winp,    // [2048][128]
    const float* __restrict__ tonic,   // [2048]
    const int*   __restrict__ Wmask,   // [2048][2048]
    const int*   __restrict__ Wsign,   // [2048][2048]
    const unsigned short* __restrict__ xhi,  // [64][512][128] bf16
    const unsigned short* __restrict__ xlo,
    unsigned short* __restrict__ rbuf, // [2][64][2048] bf16 (double buffer)
    int* __restrict__ barcnt,
    float* __restrict__ out)           // [64][512][2048]
{
  __shared__ unsigned short wlds[COLS][N_ + WPAD];   // 131584 B: W_eff slice bf16
  __shared__ unsigned short winph[COLS][I_ + IPAD];  // 8704 B
  __shared__ unsigned short winpl[COLS][I_ + IPAD];  // 8704 B
  __shared__ f32x4 red[3][2][64];                    // 6144 B: cross-wave K reduction

  const int wg   = blockIdx.x;
  const int g    = wg >> 2;        // n-block 0..63
  const int q    = wg & 3;         // b-block 0..3
  const int n0   = g * COLS;
  const int b0   = q * ROWS;
  const int tid  = threadIdx.x;
  const int wave = tid >> 6;
  const int lane = tid & 63;
  const int l15  = lane & 15;
  const int lhi  = lane >> 4;

  // ---- prologue: W_eff = relu(Wrec) * mask * sign -> bf16 LDS slice
  for (int i = tid; i < COLS * N_; i += NTHR) {
    int rr = i >> 11;                 // local n row (0..31)
    int kk = i & (N_ - 1);
    size_t gi = (size_t)(n0 + rr) * N_ + kk;
    float w = Wrec[gi];
    w = w > 0.f ? w : 0.f;
    w *= (float)(Wmask[gi] * Wsign[gi]);
    wlds[rr][kk] = f2bf_rn(w);
  }
  // Winp slice -> hi/lo bf16 LDS
  for (int i = tid; i < COLS * I_; i += NTHR) {
    int rr = i >> 7;
    int kk = i & (I_ - 1);
    float w = Winp[(size_t)(n0 + rr) * I_ + kk];
    unsigned short hh = f2bf_rn(w);
    winph[rr][kk] = hh;
    winpl[rr][kk] = f2bf_rn(w - bf2f(hh));
  }

  // wave0 owns the h state for this tile, in C/D fragment layout:
  // col = lane&15 (n), row = (lane>>4)*4 + j (b).
  float hreg[2][4];
  float ton[2] = {0.f, 0.f};
  if (wave == 0) {
    #pragma unroll
    for (int f = 0; f < 2; ++f) {
      ton[f] = tonic[n0 + f * 16 + l15];
      #pragma unroll
      for (int j = 0; j < 4; ++j) {
        int b = b0 + lhi * 4 + j;
        int n = n0 + f * 16 + l15;
        float h = h0[(size_t)b * N_ + n];
        hreg[f][j] = h;
        float r = h > 0.f ? h : 0.f;
        rbuf[(size_t)b * N_ + n] = f2bf_rn(r);   // r_0 into buffer 0
      }
    }
  }

  int phase = 1;
  gridbar(barcnt, phase * NWG);

  const float a = 0.1f;
  const float oma = 1.0f - a;

  for (int t = 0; t < T_; ++t) {
    const unsigned short* rcur = rbuf + (size_t)(t & 1) * (B_ * N_);
    unsigned short*       rnxt = rbuf + (size_t)((t + 1) & 1) * (B_ * N_);

    f32x4 acc0 = {0.f, 0.f, 0.f, 0.f};
    f32x4 acc1 = {0.f, 0.f, 0.f, 0.f};

    // ---- recurrent GEMM, K split over 4 waves (512 each)
    const int kq = wave * 512;
    const unsigned short* arow = rcur + (size_t)(b0 + l15) * N_;
    #pragma unroll
    for (int ki = 0; ki < 16; ++ki) {
      int k = kq + ki * 32 + lhi * 8;
      bf16x8 af  = *reinterpret_cast<const bf16x8*>(arow + k);           // r frag (global, L2/L3)
      bf16x8 bf0 = *reinterpret_cast<const bf16x8*>(&wlds[l15][k]);      // W frag col 0..15
      bf16x8 bf1 = *reinterpret_cast<const bf16x8*>(&wlds[16 + l15][k]); // W frag col 16..31
      acc0 = mfma16(af, bf0, acc0);
      acc1 = mfma16(af, bf1, acc1);
    }

    // ---- fused input drive: x[:,t,:] @ Winp^T, 3-pass split-bf16, i-chunk per wave
    {
      int i0 = wave * 32 + lhi * 8;
      size_t xoff = ((size_t)(b0 + l15) * T_ + t) * I_ + i0;
      bf16x8 xh  = *reinterpret_cast<const bf16x8*>(xhi + xoff);
      bf16x8 xl  = *reinterpret_cast<const bf16x8*>(xlo + xoff);
      bf16x8 wh0 = *reinterpret_cast<const bf16x8*>(&winph[l15][i0]);
      bf16x8 wl0 = *reinterpret_cast<const bf16x8*>(&winpl[l15][i0]);
      bf16x8 wh1 = *reinterpret_cast<const bf16x8*>(&winph[16 + l15][i0]);
      bf16x8 wl1 = *reinterpret_cast<const bf16x8*>(&winpl[16 + l15][i0]);
      acc0 = mfma16(xh, wh0, acc0);
      acc0 = mfma16(xh, wl0, acc0);
      acc0 = mfma16(xl, wh0, acc0);
      acc1 = mfma16(xh, wh1, acc1);
      acc1 = mfma16(xh, wl1, acc1);
      acc1 = mfma16(xl, wh1, acc1);
    }

    // ---- cross-wave reduction (waves 1..3 -> LDS, wave 0 sums)
    if (wave != 0) {
      red[wave - 1][0][lane] = acc0;
      red[wave - 1][1][lane] = acc1;
    }
    __syncthreads();
    if (wave == 0) {
      #pragma unroll
      for (int w = 0; w < 3; ++w) {
        acc0 += red[w][0][lane];
        acc1 += red[w][1][lane];
      }
      // h update + outputs
      #pragma unroll
      for (int f = 0; f < 2; ++f) {
        f32x4 accv = (f == 0) ? acc0 : acc1;
        int n = n0 + f * 16 + l15;
        #pragma unroll
        for (int j = 0; j < 4; ++j) {
          float s  = accv[j] + ton[f];
          float hn = oma * hreg[f][j] + a * s;
          hreg[f][j] = hn;
          float r = hn > 0.f ? hn : 0.f;
          int b = b0 + lhi * 4 + j;
          out[((size_t)b * T_ + t) * N_ + n] = r;
          rnxt[(size_t)b * N_ + n] = f2bf_rn(r);
        }
      }
    }
    ++phase;
    gridbar(barcnt, phase * NWG);
  }
}

extern "C" void kernel_launch(void* const* d_in, const int* in_sizes, int n_in,
                              void* d_out, int out_size, void* d_ws, size_t ws_size,
                              hipStream_t stream) {
  (void)in_sizes; (void)n_in; (void)out_size; (void)ws_size;
  const float* x     = (const float*)d_in[0];
  const float* h0    = (const float*)d_in[1];
  const float* Wrec  = (const float*)d_in[2];
  const float* Winp  = (const float*)d_in[3];
  const float* tonic = (const float*)d_in[4];
  const int*   Wmask = (const int*)d_in[5];
  const int*   Wsign = (const int*)d_in[6];
  float* out = (float*)d_out;

  char* ws = (char*)d_ws;
  const size_t nx = (size_t)B_ * T_ * I_;          // 4,194,304
  size_t off = 0;
  unsigned short* xhi = (unsigned short*)(ws + off); off += nx * 2;
  unsigned short* xlo = (unsigned short*)(ws + off); off += nx * 2;
  unsigned short* rbuf = (unsigned short*)(ws + off); off += (size_t)2 * B_ * N_ * 2;
  off = (off + 255) & ~(size_t)255;
  int* barcnt = (int*)(ws + off);

  hipMemsetAsync(barcnt, 0, 256, stream);          // graph-capturable

  int cthr = 256;
  int cblk = (int)((nx + cthr - 1) / cthr);
  k_conv_x<<<cblk, cthr, 0, stream>>>(x, xhi, xlo, (int)nx);

  rnn_persist<<<NWG, NTHR, 0, stream>>>(h0, Wrec, Winp, tonic, Wmask, Wsign,
                                        xhi, xlo, rbuf, barcnt, out);
}

// Round 3
// 6059.140 us; speedup vs baseline: 1.5479x; 1.5479x over previous
//
#include <hip/hip_runtime.h>
#include <stdint.h>
#include <stddef.h>

// mRNN persistent kernel for MI355X (gfx950).
// B=64, T=512, I=128, N=2048.
// R2: replace single-counter grid barrier (256-way atomic RMW serialization,
// ~18us/step measured) with per-WG epoch flags + group-local sync (4
// independent groups of 64 WGs; batches are independent so groups need no
// cross-sync). W_eff stays in LDS (bf16) all 512 steps.

#define B_   64
#define T_   512
#define I_   128
#define N_   2048
#define NWG  256
#define NTHR 256
#define ROWS 16   // b-rows per WG (= per group)
#define COLS 32   // n-cols per WG
#define GWG  64   // WGs per b-group (sync domain)
#define WPAD 2    // stride 2050 shorts = 1025 dwords (odd) -> 16 rows, 16 banks
#define IPAD 2    // stride 130 shorts = 65 dwords (odd)

typedef __bf16 bf16x8 __attribute__((ext_vector_type(8)));
typedef float  f32x4  __attribute__((ext_vector_type(4)));

__device__ __forceinline__ unsigned short f2bf_rn(float f) {
  unsigned int u = __float_as_uint(f);
  u += 0x7fffu + ((u >> 16) & 1u);          // round-to-nearest-even
  return (unsigned short)(u >> 16);
}
__device__ __forceinline__ float bf2f(unsigned short h) {
  return __uint_as_float(((unsigned int)h) << 16);
}

__device__ __forceinline__ f32x4 mfma16(bf16x8 a, bf16x8 b, f32x4 c) {
  return __builtin_amdgcn_mfma_f32_16x16x32_bf16(a, b, c, 0, 0, 0);
}

// x -> hi/lo bf16 split (Markidis) so drive GEMM is ~fp32-exact at MFMA speed.
__global__ void k_conv_x(const float* __restrict__ x,
                         unsigned short* __restrict__ xhi,
                         unsigned short* __restrict__ xlo, int n) {
  int i = blockIdx.x * blockDim.x + threadIdx.x;
  if (i < n) {
    float v = x[i];
    unsigned short h = f2bf_rn(v);
    xhi[i] = h;
    xlo[i] = f2bf_rn(v - bf2f(h));
  }
}

__global__ __launch_bounds__(NTHR, 1) void rnn_persist(
    const float* __restrict__ h0,      // [64][2048]
    const float* __restrict__ Wrec,    // [2048][2048]
    const float* __restrict__ Winp,    // [2048][128]
    const float* __restrict__ tonic,   // [2048]
    const int*   __restrict__ Wmask,   // [2048][2048]
    const int*   __restrict__ Wsign,   // [2048][2048]
    const unsigned short* __restrict__ xhi,  // [64][512][128] bf16
    const unsigned short* __restrict__ xlo,
    unsigned short* __restrict__ rbuf, // [2][64][2048] bf16 (double buffer)
    int* __restrict__ flags,           // [4][64] epoch flags, zeroed
    float* __restrict__ out)           // [64][512][2048]
{
  __shared__ unsigned short wlds[COLS][N_ + WPAD];   // 131200 B: W_eff slice bf16
  __shared__ unsigned short winph[COLS][I_ + IPAD];  // 8320 B
  __shared__ unsigned short winpl[COLS][I_ + IPAD];  // 8320 B
  __shared__ f32x4 red[3][2][64];                    // 6144 B: cross-wave K reduction

  const int wg   = blockIdx.x;
  const int g    = wg >> 2;        // n-block 0..63 (rank within group)
  const int q    = wg & 3;         // b-group 0..3 (sync domain)
  const int n0   = g * COLS;
  const int b0   = q * ROWS;
  const int tid  = threadIdx.x;
  const int wave = tid >> 6;
  const int lane = tid & 63;
  const int l15  = lane & 15;
  const int lhi  = lane >> 4;
  int* gflags = flags + q * GWG;   // this group's 64 epoch flags

  // ---- prologue: W_eff = relu(Wrec) * mask * sign -> bf16 LDS slice
  for (int i = tid; i < COLS * N_; i += NTHR) {
    int rr = i >> 11;                 // local n row (0..31)
    int kk = i & (N_ - 1);
    size_t gi = (size_t)(n0 + rr) * N_ + kk;
    float w = Wrec[gi];
    w = w > 0.f ? w : 0.f;
    w *= (float)(Wmask[gi] * Wsign[gi]);
    wlds[rr][kk] = f2bf_rn(w);
  }
  // Winp slice -> hi/lo bf16 LDS
  for (int i = tid; i < COLS * I_; i += NTHR) {
    int rr = i >> 7;
    int kk = i & (I_ - 1);
    float w = Winp[(size_t)(n0 + rr) * I_ + kk];
    unsigned short hh = f2bf_rn(w);
    winph[rr][kk] = hh;
    winpl[rr][kk] = f2bf_rn(w - bf2f(hh));
  }

  // wave0 owns the h state for this tile, in C/D fragment layout:
  // col = lane&15 (n), row = (lane>>4)*4 + j (b).
  float hreg[2][4];
  float ton[2] = {0.f, 0.f};
  if (wave == 0) {
    #pragma unroll
    for (int f = 0; f < 2; ++f) {
      ton[f] = tonic[n0 + f * 16 + l15];
      #pragma unroll
      for (int j = 0; j < 4; ++j) {
        int b = b0 + lhi * 4 + j;
        int n = n0 + f * 16 + l15;
        float h = h0[(size_t)b * N_ + n];
        hreg[f][j] = h;
        float r = h > 0.f ? h : 0.f;
        rbuf[(size_t)b * N_ + n] = f2bf_rn(r);   // r_0 into buffer 0
      }
    }
  }

  // ---- group barrier, epoch 1: r_0 slices visible within group
  __syncthreads();
  if (wave == 0) {
    if (lane == 0)
      __hip_atomic_store(&gflags[g], 1, __ATOMIC_RELEASE, __HIP_MEMORY_SCOPE_AGENT);
    while (__hip_atomic_load(&gflags[lane], __ATOMIC_RELAXED, __HIP_MEMORY_SCOPE_AGENT) < 1)
      __builtin_amdgcn_s_sleep(1);
    __builtin_amdgcn_fence(__ATOMIC_ACQUIRE, "agent");
  }
  __syncthreads();

  const float a = 0.1f;
  const float oma = 1.0f - a;

  for (int t = 0; t < T_; ++t) {
    const unsigned short* rcur = rbuf + (size_t)(t & 1) * (B_ * N_);
    unsigned short*       rnxt = rbuf + (size_t)((t + 1) & 1) * (B_ * N_);

    f32x4 acc0 = {0.f, 0.f, 0.f, 0.f};
    f32x4 acc1 = {0.f, 0.f, 0.f, 0.f};

    // ---- recurrent GEMM, K split over 4 waves (512 each)
    const int kq = wave * 512;
    const unsigned short* arow = rcur + (size_t)(b0 + l15) * N_;
    #pragma unroll
    for (int ki = 0; ki < 16; ++ki) {
      int k = kq + ki * 32 + lhi * 8;
      bf16x8 af  = *reinterpret_cast<const bf16x8*>(arow + k);           // r frag (LLC)
      bf16x8 bf0 = *reinterpret_cast<const bf16x8*>(&wlds[l15][k]);      // W frag col 0..15
      bf16x8 bf1 = *reinterpret_cast<const bf16x8*>(&wlds[16 + l15][k]); // W frag col 16..31
      acc0 = mfma16(af, bf0, acc0);
      acc1 = mfma16(af, bf1, acc1);
    }

    // ---- fused input drive: x[:,t,:] @ Winp^T, 3-pass split-bf16, i-chunk per wave
    {
      int i0 = wave * 32 + lhi * 8;
      size_t xoff = ((size_t)(b0 + l15) * T_ + t) * I_ + i0;
      bf16x8 xh  = *reinterpret_cast<const bf16x8*>(xhi + xoff);
      bf16x8 xl  = *reinterpret_cast<const bf16x8*>(xlo + xoff);
      bf16x8 wh0 = *reinterpret_cast<const bf16x8*>(&winph[l15][i0]);
      bf16x8 wl0 = *reinterpret_cast<const bf16x8*>(&winpl[l15][i0]);
      bf16x8 wh1 = *reinterpret_cast<const bf16x8*>(&winph[16 + l15][i0]);
      bf16x8 wl1 = *reinterpret_cast<const bf16x8*>(&winpl[16 + l15][i0]);
      acc0 = mfma16(xh, wh0, acc0);
      acc0 = mfma16(xh, wl0, acc0);
      acc0 = mfma16(xl, wh0, acc0);
      acc1 = mfma16(xh, wh1, acc1);
      acc1 = mfma16(xh, wl1, acc1);
      acc1 = mfma16(xl, wh1, acc1);
    }

    // ---- cross-wave reduction (waves 1..3 -> LDS, wave 0 sums)
    if (wave != 0) {
      red[wave - 1][0][lane] = acc0;
      red[wave - 1][1][lane] = acc1;
    }
    __syncthreads();
    if (wave == 0) {
      #pragma unroll
      for (int w = 0; w < 3; ++w) {
        acc0 += red[w][0][lane];
        acc1 += red[w][1][lane];
      }
      // h update + outputs
      #pragma unroll
      for (int f = 0; f < 2; ++f) {
        f32x4 accv = (f == 0) ? acc0 : acc1;
        int n = n0 + f * 16 + l15;
        #pragma unroll
        for (int j = 0; j < 4; ++j) {
          float s  = accv[j] + ton[f];
          float hn = oma * hreg[f][j] + a * s;
          hreg[f][j] = hn;
          float r = hn > 0.f ? hn : 0.f;
          int b = b0 + lhi * 4 + j;
          out[((size_t)b * T_ + t) * N_ + n] = r;
          rnxt[(size_t)b * N_ + n] = f2bf_rn(r);
        }
      }
    }

    // ---- group barrier, epoch t+2: flag release-store + 64-lane poll
    __syncthreads();                 // waves 1-3 done (their reads consumed)
    if (wave == 0) {
      const int epoch = t + 2;
      if (lane == 0)
        __hip_atomic_store(&gflags[g], epoch, __ATOMIC_RELEASE, __HIP_MEMORY_SCOPE_AGENT);
      while (__hip_atomic_load(&gflags[lane], __ATOMIC_RELAXED, __HIP_MEMORY_SCOPE_AGENT) < epoch)
        __builtin_amdgcn_s_sleep(1);
      __builtin_amdgcn_fence(__ATOMIC_ACQUIRE, "agent");
    }
    __syncthreads();
  }
}

extern "C" void kernel_launch(void* const* d_in, const int* in_sizes, int n_in,
                              void* d_out, int out_size, void* d_ws, size_t ws_size,
                              hipStream_t stream) {
  (void)in_sizes; (void)n_in; (void)out_size; (void)ws_size;
  const float* x     = (const float*)d_in[0];
  const float* h0    = (const float*)d_in[1];
  const float* Wrec  = (const float*)d_in[2];
  const float* Winp  = (const float*)d_in[3];
  const float* tonic = (const float*)d_in[4];
  const int*   Wmask = (const int*)d_in[5];
  const int*   Wsign = (const int*)d_in[6];
  float* out = (float*)d_out;

  char* ws = (char*)d_ws;
  const size_t nx = (size_t)B_ * T_ * I_;          // 4,194,304
  size_t off = 0;
  unsigned short* xhi = (unsigned short*)(ws + off); off += nx * 2;
  unsigned short* xlo = (unsigned short*)(ws + off); off += nx * 2;
  unsigned short* rbuf = (unsigned short*)(ws + off); off += (size_t)2 * B_ * N_ * 2;
  off = (off + 255) & ~(size_t)255;
  int* flags = (int*)(ws + off);                   // [4][64] epochs

  hipMemsetAsync(flags, 0, 4 * GWG * sizeof(int), stream);  // graph-capturable

  int cthr = 256;
  int cblk = (int)((nx + cthr - 1) / cthr);
  k_conv_x<<<cblk, cthr, 0, stream>>>(x, xhi, xlo, (int)nx);

  rnn_persist<<<NWG, NTHR, 0, stream>>>(h0, Wrec, Winp, tonic, Wmask, Wsign,
                                        xhi, xlo, rbuf, flags, out);
}

// Round 4
// 5372.033 us; speedup vs baseline: 1.7459x; 1.1279x over previous
//
#include <hip/hip_runtime.h>
#include <stdint.h>
#include <stddef.h>

// mRNN persistent kernel for MI355X (gfx950).
// B=64, T=512, I=128, N=2048.
// R3: fence-free step exchange. All cross-WG data (r, flags) moves via
// agent-scope RELAXED atomics (sc1 -> coherence point / MALL), so the per-step
// buffer_wbl2 / buffer_inv pair of R2's release/acquire (the measured 11.6us
// step cost) disappears. Epoch protocol identical to R2. WPAD back to 8
// (measured: WPAD=2 doubled LDS bank conflicts).

#define B_   64
#define T_   512
#define I_   128
#define N_   2048
#define NWG  256
#define NTHR 256
#define ROWS 16   // b-rows per WG (= per group)
#define COLS 32   // n-cols per WG
#define GWG  64   // WGs per b-group (sync domain)
#define WPAD 8    // stride 2056 shorts = 1028 dwords == 4 (mod 32): even b128 banks
#define IPAD 8

typedef __bf16 bf16x8 __attribute__((ext_vector_type(8)));
typedef float  f32x4  __attribute__((ext_vector_type(4)));

__device__ __forceinline__ unsigned short f2bf_rn(float f) {
  unsigned int u = __float_as_uint(f);
  u += 0x7fffu + ((u >> 16) & 1u);          // round-to-nearest-even
  return (unsigned short)(u >> 16);
}
__device__ __forceinline__ float bf2f(unsigned short h) {
  return __uint_as_float(((unsigned int)h) << 16);
}

__device__ __forceinline__ f32x4 mfma16(bf16x8 a, bf16x8 b, f32x4 c) {
  return __builtin_amdgcn_mfma_f32_16x16x32_bf16(a, b, c, 0, 0, 0);
}

// agent-scope coherent bf16x8 load as 4 relaxed dword atomics (sc1: bypasses
// stale L1/L2, reads coherence point; compiler keeps waitcnt pipelining).
__device__ __forceinline__ bf16x8 coh_load8(const unsigned short* p) {
  union { unsigned int u[4]; bf16x8 v; } r;
  unsigned int* a = (unsigned int*)p;
  #pragma unroll
  for (int j = 0; j < 4; ++j)
    r.u[j] = __hip_atomic_load(a + j, __ATOMIC_RELAXED, __HIP_MEMORY_SCOPE_AGENT);
  return r.v;
}

// x -> hi/lo bf16 split (Markidis) so drive GEMM is ~fp32-exact at MFMA speed.
__global__ void k_conv_x(const float* __restrict__ x,
                         unsigned short* __restrict__ xhi,
                         unsigned short* __restrict__ xlo, int n) {
  int i = blockIdx.x * blockDim.x + threadIdx.x;
  if (i < n) {
    float v = x[i];
    unsigned short h = f2bf_rn(v);
    xhi[i] = h;
    xlo[i] = f2bf_rn(v - bf2f(h));
  }
}

__global__ __launch_bounds__(NTHR, 1) void rnn_persist(
    const float* __restrict__ h0,      // [64][2048]
    const float* __restrict__ Wrec,    // [2048][2048]
    const float* __restrict__ Winp,    // [2048][128]
    const float* __restrict__ tonic,   // [2048]
    const int*   __restrict__ Wmask,   // [2048][2048]
    const int*   __restrict__ Wsign,   // [2048][2048]
    const unsigned short* __restrict__ xhi,  // [64][512][128] bf16
    const unsigned short* __restrict__ xlo,
    unsigned short* __restrict__ rbuf, // [2][64][2048] bf16 (double buffer)
    int* __restrict__ flags,           // [4][64] epoch flags, zeroed
    float* __restrict__ out)           // [64][512][2048]
{
  __shared__ unsigned short wlds[COLS][N_ + WPAD];   // 131584 B: W_eff slice bf16
  __shared__ unsigned short winph[COLS][I_ + IPAD];  // 8704 B
  __shared__ unsigned short winpl[COLS][I_ + IPAD];  // 8704 B
  __shared__ f32x4 red[3][2][64];                    // 6144 B: cross-wave K reduction

  const int wg   = blockIdx.x;
  const int g    = wg >> 2;        // n-block 0..63 (rank within group)
  const int q    = wg & 3;         // b-group 0..3 (sync domain)
  const int n0   = g * COLS;
  const int b0   = q * ROWS;
  const int tid  = threadIdx.x;
  const int wave = tid >> 6;
  const int lane = tid & 63;
  const int l15  = lane & 15;
  const int lhi  = lane >> 4;
  int* gflags = flags + q * GWG;   // this group's 64 epoch flags

  // ---- prologue: W_eff = relu(Wrec) * mask * sign -> bf16 LDS slice
  for (int i = tid; i < COLS * N_; i += NTHR) {
    int rr = i >> 11;                 // local n row (0..31)
    int kk = i & (N_ - 1);
    size_t gi = (size_t)(n0 + rr) * N_ + kk;
    float w = Wrec[gi];
    w = w > 0.f ? w : 0.f;
    w *= (float)(Wmask[gi] * Wsign[gi]);
    wlds[rr][kk] = f2bf_rn(w);
  }
  // Winp slice -> hi/lo bf16 LDS
  for (int i = tid; i < COLS * I_; i += NTHR) {
    int rr = i >> 7;
    int kk = i & (I_ - 1);
    float w = Winp[(size_t)(n0 + rr) * I_ + kk];
    unsigned short hh = f2bf_rn(w);
    winph[rr][kk] = hh;
    winpl[rr][kk] = f2bf_rn(w - bf2f(hh));
  }

  // wave0 owns the h state for this tile, in C/D fragment layout:
  // col = lane&15 (n), row = (lane>>4)*4 + j (b).
  float hreg[2][4];
  float ton[2] = {0.f, 0.f};
  if (wave == 0) {
    #pragma unroll
    for (int f = 0; f < 2; ++f) {
      ton[f] = tonic[n0 + f * 16 + l15];
      #pragma unroll
      for (int j = 0; j < 4; ++j) {
        int b = b0 + lhi * 4 + j;
        int n = n0 + f * 16 + l15;
        float h = h0[(size_t)b * N_ + n];
        hreg[f][j] = h;
        float r = h > 0.f ? h : 0.f;
        __hip_atomic_store(&rbuf[(size_t)b * N_ + n], f2bf_rn(r),
                           __ATOMIC_RELAXED, __HIP_MEMORY_SCOPE_AGENT);
      }
    }
  }

  // ---- group sync, epoch 1: r_0 visible at coherence point
  __syncthreads();
  if (wave == 0) {
    asm volatile("s_waitcnt vmcnt(0)" ::: "memory");
    if (lane == 0)
      __hip_atomic_store(&gflags[g], 1, __ATOMIC_RELAXED, __HIP_MEMORY_SCOPE_AGENT);
    while (__hip_atomic_load(&gflags[lane], __ATOMIC_RELAXED, __HIP_MEMORY_SCOPE_AGENT) < 1)
      __builtin_amdgcn_s_sleep(1);
    asm volatile("" ::: "memory");
  }
  __syncthreads();

  const float a = 0.1f;
  const float oma = 1.0f - a;

  for (int t = 0; t < T_; ++t) {
    const unsigned short* rcur = rbuf + (size_t)(t & 1) * (B_ * N_);
    unsigned short*       rnxt = rbuf + (size_t)((t + 1) & 1) * (B_ * N_);

    f32x4 acc0 = {0.f, 0.f, 0.f, 0.f};
    f32x4 acc1 = {0.f, 0.f, 0.f, 0.f};

    // ---- recurrent GEMM, K split over 4 waves (512 each)
    const int kq = wave * 512;
    const unsigned short* arow = rcur + (size_t)(b0 + l15) * N_;
    #pragma unroll
    for (int ki = 0; ki < 16; ++ki) {
      int k = kq + ki * 32 + lhi * 8;
      bf16x8 af  = coh_load8(arow + k);                                  // r frag (MALL)
      bf16x8 bf0 = *reinterpret_cast<const bf16x8*>(&wlds[l15][k]);      // W frag col 0..15
      bf16x8 bf1 = *reinterpret_cast<const bf16x8*>(&wlds[16 + l15][k]); // W frag col 16..31
      acc0 = mfma16(af, bf0, acc0);
      acc1 = mfma16(af, bf1, acc1);
    }

    // ---- fused input drive: x[:,t,:] @ Winp^T, 3-pass split-bf16, i-chunk per wave
    {
      int i0 = wave * 32 + lhi * 8;
      size_t xoff = ((size_t)(b0 + l15) * T_ + t) * I_ + i0;
      bf16x8 xh  = *reinterpret_cast<const bf16x8*>(xhi + xoff);
      bf16x8 xl  = *reinterpret_cast<const bf16x8*>(xlo + xoff);
      bf16x8 wh0 = *reinterpret_cast<const bf16x8*>(&winph[l15][i0]);
      bf16x8 wl0 = *reinterpret_cast<const bf16x8*>(&winpl[l15][i0]);
      bf16x8 wh1 = *reinterpret_cast<const bf16x8*>(&winph[16 + l15][i0]);
      bf16x8 wl1 = *reinterpret_cast<const bf16x8*>(&winpl[16 + l15][i0]);
      acc0 = mfma16(xh, wh0, acc0);
      acc0 = mfma16(xh, wl0, acc0);
      acc0 = mfma16(xl, wh0, acc0);
      acc1 = mfma16(xh, wh1, acc1);
      acc1 = mfma16(xh, wl1, acc1);
      acc1 = mfma16(xl, wh1, acc1);
    }

    // ---- cross-wave reduction (waves 1..3 -> LDS, wave 0 sums)
    if (wave != 0) {
      red[wave - 1][0][lane] = acc0;
      red[wave - 1][1][lane] = acc1;
    }
    __syncthreads();   // also: all waves' rcur reads complete past this point
    if (wave == 0) {
      #pragma unroll
      for (int w = 0; w < 3; ++w) {
        acc0 += red[w][0][lane];
        acc1 += red[w][1][lane];
      }
      float rvals[2][4];
      // h update + coherent rnxt stores (issue first: they gate the flag)
      #pragma unroll
      for (int f = 0; f < 2; ++f) {
        f32x4 accv = (f == 0) ? acc0 : acc1;
        int n = n0 + f * 16 + l15;
        #pragma unroll
        for (int j = 0; j < 4; ++j) {
          float s  = accv[j] + ton[f];
          float hn = oma * hreg[f][j] + a * s;
          hreg[f][j] = hn;
          float r = hn > 0.f ? hn : 0.f;
          rvals[f][j] = r;
          int b = b0 + lhi * 4 + j;
          __hip_atomic_store(&rnxt[(size_t)b * N_ + n], f2bf_rn(r),
                             __ATOMIC_RELAXED, __HIP_MEMORY_SCOPE_AGENT);
        }
      }
      // drain rnxt to coherence point, then publish epoch
      asm volatile("s_waitcnt vmcnt(0)" ::: "memory");
      const int epoch = t + 2;
      if (lane == 0)
        __hip_atomic_store(&gflags[g], epoch, __ATOMIC_RELAXED, __HIP_MEMORY_SCOPE_AGENT);
      // out stores after the flag: drain overlaps peers' polls
      #pragma unroll
      for (int f = 0; f < 2; ++f) {
        int n = n0 + f * 16 + l15;
        #pragma unroll
        for (int j = 0; j < 4; ++j) {
          int b = b0 + lhi * 4 + j;
          out[((size_t)b * T_ + t) * N_ + n] = rvals[f][j];
        }
      }
      // wait for all group peers
      while (__hip_atomic_load(&gflags[lane], __ATOMIC_RELAXED, __HIP_MEMORY_SCOPE_AGENT) < epoch)
        __builtin_amdgcn_s_sleep(1);
      asm volatile("" ::: "memory");   // no load of rnxt-data may be hoisted above
    }
    __syncthreads();
  }
}

extern "C" void kernel_launch(void* const* d_in, const int* in_sizes, int n_in,
                              void* d_out, int out_size, void* d_ws, size_t ws_size,
                              hipStream_t stream) {
  (void)in_sizes; (void)n_in; (void)out_size; (void)ws_size;
  const float* x     = (const float*)d_in[0];
  const float* h0    = (const float*)d_in[1];
  const float* Wrec  = (const float*)d_in[2];
  const float* Winp  = (const float*)d_in[3];
  const float* tonic = (const float*)d_in[4];
  const int*   Wmask = (const int*)d_in[5];
  const int*   Wsign = (const int*)d_in[6];
  float* out = (float*)d_out;

  char* ws = (char*)d_ws;
  const size_t nx = (size_t)B_ * T_ * I_;          // 4,194,304
  size_t off = 0;
  unsigned short* xhi = (unsigned short*)(ws + off); off += nx * 2;
  unsigned short* xlo = (unsigned short*)(ws + off); off += nx * 2;
  unsigned short* rbuf = (unsigned short*)(ws + off); off += (size_t)2 * B_ * N_ * 2;
  off = (off + 255) & ~(size_t)255;
  int* flags = (int*)(ws + off);                   // [4][64] epochs

  hipMemsetAsync(flags, 0, 4 * GWG * sizeof(int), stream);  // graph-capturable

  int cthr = 256;
  int cblk = (int)((nx + cthr - 1) / cthr);
  k_conv_x<<<cblk, cthr, 0, stream>>>(x, xhi, xlo, (int)nx);

  rnn_persist<<<NWG, NTHR, 0, stream>>>(h0, Wrec, Winp, tonic, Wmask, Wsign,
                                        xhi, xlo, rbuf, flags, out);
}

// Round 5
// 3605.828 us; speedup vs baseline: 2.6011x; 1.4898x over previous
//
#include <hip/hip_runtime.h>
#include <stdint.h>
#include <stddef.h>

// mRNN persistent kernel for MI355X (gfx950).
// B=64, T=512, I=128, N=2048.
// R4: r-exchange via wide coherent loads. R3 used per-element relaxed-atomic
// dword loads (65k coherence requests/step) -> request-rate bound at TCC/MALL.
// Now: inline-asm global_load_dwordx4 sc0 sc1 (16B/request, pipelined, still
// bypasses stale L1/L2), HK-style issue-all -> vmcnt(0) -> sched_barrier ->
// consume. Flag poll reads 4 flags/lane via dwordx4. out stores moved after
// poll (drain overlaps next step's loads). Protocol identical to R3.

#define B_   64
#define T_   512
#define I_   128
#define N_   2048
#define NWG  256
#define NTHR 256
#define ROWS 16   // b-rows per WG (= per group)
#define COLS 32   // n-cols per WG
#define GWG  64   // WGs per b-group (sync domain)
#define WPAD 8
#define IPAD 8

typedef __bf16 bf16x8 __attribute__((ext_vector_type(8)));
typedef float  f32x4  __attribute__((ext_vector_type(4)));
typedef int    i32x4  __attribute__((ext_vector_type(4)));

__device__ __forceinline__ unsigned short f2bf_rn(float f) {
  unsigned int u = __float_as_uint(f);
  u += 0x7fffu + ((u >> 16) & 1u);          // round-to-nearest-even
  return (unsigned short)(u >> 16);
}
__device__ __forceinline__ float bf2f(unsigned short h) {
  return __uint_as_float(((unsigned int)h) << 16);
}

__device__ __forceinline__ f32x4 mfma16(bf16x8 a, bf16x8 b, f32x4 c) {
  return __builtin_amdgcn_mfma_f32_16x16x32_bf16(a, b, c, 0, 0, 0);
}

// coherent 16B load: bypasses L1/L2 (sc0 sc1), reads coherence point.
// NO waitcnt inside -- caller batches loads then drains once (HK pattern).
__device__ __forceinline__ bf16x8 coh_load16(const unsigned short* p) {
  bf16x8 r;
  asm volatile("global_load_dwordx4 %0, %1, off sc0 sc1"
               : "=v"(r) : "v"(p) : "memory");
  return r;
}

__device__ __forceinline__ i32x4 coh_load_flags(const int* p) {
  i32x4 r;
  asm volatile("global_load_dwordx4 %0, %1, off sc0 sc1"
               : "=v"(r) : "v"(p) : "memory");
  asm volatile("s_waitcnt vmcnt(0)" ::: "memory");
  return r;
}

// x -> hi/lo bf16 split (Markidis) so drive GEMM is ~fp32-exact at MFMA speed.
__global__ void k_conv_x(const float* __restrict__ x,
                         unsigned short* __restrict__ xhi,
                         unsigned short* __restrict__ xlo, int n) {
  int i = blockIdx.x * blockDim.x + threadIdx.x;
  if (i < n) {
    float v = x[i];
    unsigned short h = f2bf_rn(v);
    xhi[i] = h;
    xlo[i] = f2bf_rn(v - bf2f(h));
  }
}

__global__ __launch_bounds__(NTHR, 1) void rnn_persist(
    const float* __restrict__ h0,      // [64][2048]
    const float* __restrict__ Wrec,    // [2048][2048]
    const float* __restrict__ Winp,    // [2048][128]
    const float* __restrict__ tonic,   // [2048]
    const int*   __restrict__ Wmask,   // [2048][2048]
    const int*   __restrict__ Wsign,   // [2048][2048]
    const unsigned short* __restrict__ xhi,  // [64][512][128] bf16
    const unsigned short* __restrict__ xlo,
    unsigned short* __restrict__ rbuf, // [2][64][2048] bf16 (double buffer)
    int* __restrict__ flags,           // [4][64] epoch flags, zeroed
    float* __restrict__ out)           // [64][512][2048]
{
  __shared__ unsigned short wlds[COLS][N_ + WPAD];   // 131584 B: W_eff slice bf16
  __shared__ unsigned short winph[COLS][I_ + IPAD];  // 8704 B
  __shared__ unsigned short winpl[COLS][I_ + IPAD];  // 8704 B
  __shared__ f32x4 red[3][2][64];                    // 6144 B: cross-wave K reduction

  const int wg   = blockIdx.x;
  const int g    = wg >> 2;        // n-block 0..63 (rank within group)
  const int q    = wg & 3;         // b-group 0..3 (sync domain; XCDs {q,q+4})
  const int n0   = g * COLS;
  const int b0   = q * ROWS;
  const int tid  = threadIdx.x;
  const int wave = tid >> 6;
  const int lane = tid & 63;
  const int l15  = lane & 15;
  const int lhi  = lane >> 4;
  int* gflags = flags + q * GWG;   // this group's 64 epoch flags

  // ---- prologue: W_eff = relu(Wrec) * mask * sign -> bf16 LDS slice
  for (int i = tid; i < COLS * N_; i += NTHR) {
    int rr = i >> 11;                 // local n row (0..31)
    int kk = i & (N_ - 1);
    size_t gi = (size_t)(n0 + rr) * N_ + kk;
    float w = Wrec[gi];
    w = w > 0.f ? w : 0.f;
    w *= (float)(Wmask[gi] * Wsign[gi]);
    wlds[rr][kk] = f2bf_rn(w);
  }
  // Winp slice -> hi/lo bf16 LDS
  for (int i = tid; i < COLS * I_; i += NTHR) {
    int rr = i >> 7;
    int kk = i & (I_ - 1);
    float w = Winp[(size_t)(n0 + rr) * I_ + kk];
    unsigned short hh = f2bf_rn(w);
    winph[rr][kk] = hh;
    winpl[rr][kk] = f2bf_rn(w - bf2f(hh));
  }

  // wave0 owns the h state for this tile, in C/D fragment layout:
  // col = lane&15 (n), row = (lane>>4)*4 + j (b).
  float hreg[2][4];
  float ton[2] = {0.f, 0.f};
  if (wave == 0) {
    #pragma unroll
    for (int f = 0; f < 2; ++f) {
      ton[f] = tonic[n0 + f * 16 + l15];
      #pragma unroll
      for (int j = 0; j < 4; ++j) {
        int b = b0 + lhi * 4 + j;
        int n = n0 + f * 16 + l15;
        float h = h0[(size_t)b * N_ + n];
        hreg[f][j] = h;
        float r = h > 0.f ? h : 0.f;
        __hip_atomic_store(&rbuf[(size_t)b * N_ + n], f2bf_rn(r),
                           __ATOMIC_RELAXED, __HIP_MEMORY_SCOPE_AGENT);
      }
    }
  }

  // ---- group sync, epoch 1: r_0 visible at coherence point
  __syncthreads();
  if (wave == 0) {
    asm volatile("s_waitcnt vmcnt(0)" ::: "memory");
    if (lane == 0)
      __hip_atomic_store(&gflags[g], 1, __ATOMIC_RELAXED, __HIP_MEMORY_SCOPE_AGENT);
    const int* fp = gflags + l15 * 4;
    for (;;) {
      i32x4 f = coh_load_flags(fp);
      bool ok = (f[0] >= 1) && (f[1] >= 1) && (f[2] >= 1) && (f[3] >= 1);
      if (__all(ok)) break;
      __builtin_amdgcn_s_sleep(1);
    }
    asm volatile("" ::: "memory");
  }
  __syncthreads();

  const float a = 0.1f;
  const float oma = 1.0f - a;

  for (int t = 0; t < T_; ++t) {
    const unsigned short* rcur = rbuf + (size_t)(t & 1) * (B_ * N_);
    unsigned short*       rnxt = rbuf + (size_t)((t + 1) & 1) * (B_ * N_);

    f32x4 acc0 = {0.f, 0.f, 0.f, 0.f};
    f32x4 acc1 = {0.f, 0.f, 0.f, 0.f};

    // ---- recurrent GEMM, K split over 4 waves (512 each)
    // phase 1: issue all 16 coherent A-frag loads (16 outstanding)
    const int kq = wave * 512;
    const unsigned short* arow = rcur + (size_t)(b0 + l15) * N_;
    bf16x8 afr[16];
    #pragma unroll
    for (int ki = 0; ki < 16; ++ki) {
      afr[ki] = coh_load16(arow + kq + ki * 32 + lhi * 8);
    }
    // single drain + scheduling fence (rule #18), then consume
    asm volatile("s_waitcnt vmcnt(0)" ::: "memory");
    __builtin_amdgcn_sched_barrier(0);
    #pragma unroll
    for (int ki = 0; ki < 16; ++ki) {
      int k = kq + ki * 32 + lhi * 8;
      bf16x8 bf0 = *reinterpret_cast<const bf16x8*>(&wlds[l15][k]);      // W frag col 0..15
      bf16x8 bf1 = *reinterpret_cast<const bf16x8*>(&wlds[16 + l15][k]); // W frag col 16..31
      acc0 = mfma16(afr[ki], bf0, acc0);
      acc1 = mfma16(afr[ki], bf1, acc1);
    }

    // ---- fused input drive: x[:,t,:] @ Winp^T, 3-pass split-bf16, i-chunk per wave
    {
      int i0 = wave * 32 + lhi * 8;
      size_t xoff = ((size_t)(b0 + l15) * T_ + t) * I_ + i0;
      bf16x8 xh  = *reinterpret_cast<const bf16x8*>(xhi + xoff);
      bf16x8 xl  = *reinterpret_cast<const bf16x8*>(xlo + xoff);
      bf16x8 wh0 = *reinterpret_cast<const bf16x8*>(&winph[l15][i0]);
      bf16x8 wl0 = *reinterpret_cast<const bf16x8*>(&winpl[l15][i0]);
      bf16x8 wh1 = *reinterpret_cast<const bf16x8*>(&winph[16 + l15][i0]);
      bf16x8 wl1 = *reinterpret_cast<const bf16x8*>(&winpl[16 + l15][i0]);
      acc0 = mfma16(xh, wh0, acc0);
      acc0 = mfma16(xh, wl0, acc0);
      acc0 = mfma16(xl, wh0, acc0);
      acc1 = mfma16(xh, wh1, acc1);
      acc1 = mfma16(xh, wl1, acc1);
      acc1 = mfma16(xl, wh1, acc1);
    }

    // ---- cross-wave reduction (waves 1..3 -> LDS, wave 0 sums)
    if (wave != 0) {
      red[wave - 1][0][lane] = acc0;
      red[wave - 1][1][lane] = acc1;
    }
    __syncthreads();   // all waves' rcur reads complete past this point
    if (wave == 0) {
      #pragma unroll
      for (int w = 0; w < 3; ++w) {
        acc0 += red[w][0][lane];
        acc1 += red[w][1][lane];
      }
      float rvals[2][4];
      // h update + coherent rnxt stores (they gate the flag)
      #pragma unroll
      for (int f = 0; f < 2; ++f) {
        f32x4 accv = (f == 0) ? acc0 : acc1;
        int n = n0 + f * 16 + l15;
        #pragma unroll
        for (int j = 0; j < 4; ++j) {
          float s  = accv[j] + ton[f];
          float hn = oma * hreg[f][j] + a * s;
          hreg[f][j] = hn;
          float r = hn > 0.f ? hn : 0.f;
          rvals[f][j] = r;
          int b = b0 + lhi * 4 + j;
          __hip_atomic_store(&rnxt[(size_t)b * N_ + n], f2bf_rn(r),
                             __ATOMIC_RELAXED, __HIP_MEMORY_SCOPE_AGENT);
        }
      }
      // drain rnxt to coherence point, then publish epoch
      asm volatile("s_waitcnt vmcnt(0)" ::: "memory");
      const int epoch = t + 2;
      if (lane == 0)
        __hip_atomic_store(&gflags[g], epoch, __ATOMIC_RELAXED, __HIP_MEMORY_SCOPE_AGENT);
      // wait for all group peers: 4 flags per lane via dwordx4
      const int* fp = gflags + l15 * 4;
      for (;;) {
        i32x4 f = coh_load_flags(fp);
        bool ok = (f[0] >= epoch) && (f[1] >= epoch) && (f[2] >= epoch) && (f[3] >= epoch);
        if (__all(ok)) break;
        __builtin_amdgcn_s_sleep(1);
      }
      asm volatile("" ::: "memory");   // no rnxt-data load may be hoisted above
      // out stores AFTER poll: drain overlaps next step's A-load RTT
      #pragma unroll
      for (int f = 0; f < 2; ++f) {
        int n = n0 + f * 16 + l15;
        #pragma unroll
        for (int j = 0; j < 4; ++j) {
          int b = b0 + lhi * 4 + j;
          out[((size_t)b * T_ + t) * N_ + n] = rvals[f][j];
        }
      }
    }
    __syncthreads();
  }
}

extern "C" void kernel_launch(void* const* d_in, const int* in_sizes, int n_in,
                              void* d_out, int out_size, void* d_ws, size_t ws_size,
                              hipStream_t stream) {
  (void)in_sizes; (void)n_in; (void)out_size; (void)ws_size;
  const float* x     = (const float*)d_in[0];
  const float* h0    = (const float*)d_in[1];
  const float* Wrec  = (const float*)d_in[2];
  const float* Winp  = (const float*)d_in[3];
  const float* tonic = (const float*)d_in[4];
  const int*   Wmask = (const int*)d_in[5];
  const int*   Wsign = (const int*)d_in[6];
  float* out = (float*)d_out;

  char* ws = (char*)d_ws;
  const size_t nx = (size_t)B_ * T_ * I_;          // 4,194,304
  size_t off = 0;
  unsigned short* xhi = (unsigned short*)(ws + off); off += nx * 2;
  unsigned short* xlo = (unsigned short*)(ws + off); off += nx * 2;
  unsigned short* rbuf = (unsigned short*)(ws + off); off += (size_t)2 * B_ * N_ * 2;
  off = (off + 255) & ~(size_t)255;
  int* flags = (int*)(ws + off);                   // [4][64] epochs

  hipMemsetAsync(flags, 0, 4 * GWG * sizeof(int), stream);  // graph-capturable

  int cthr = 256;
  int cblk = (int)((nx + cthr - 1) / cthr);
  k_conv_x<<<cblk, cthr, 0, stream>>>(x, xhi, xlo, (int)nx);

  rnn_persist<<<NWG, NTHR, 0, stream>>>(h0, Wrec, Winp, tonic, Wmask, Wsign,
                                        xhi, xlo, rbuf, flags, out);
}

// Round 9
// 2934.035 us; speedup vs baseline: 3.1966x; 1.2290x over previous
//
#include <hip/hip_runtime.h>
#include <stdint.h>
#include <stddef.h>

// mRNN persistent kernel for MI355X (gfx950).
// B=64, T=512, I=128, N=2048.
// R5: hierarchical group sync. Evidence R1->R4: step time scales with poll
// request count into the (few) flag cache lines -> hot-line queueing at the
// coherence point. Now only 1 aggregator WG per group polls the 64 per-WG
// flags; it publishes a single done[q] word; the other 63 WGs poll that one
// word with all 64 lanes at the SAME address (1 coalesced request/iter).
// Data path identical to R4 (coherent dwordx4 r-exchange, batched loads).

#define B_   64
#define T_   512
#define I_   128
#define N_   2048
#define NWG  256
#define NTHR 256
#define ROWS 16   // b-rows per WG (= per group)
#define COLS 32   // n-cols per WG
#define GWG  64   // WGs per b-group (sync domain)
#define WPAD 8
#define IPAD 8

typedef __bf16 bf16x8 __attribute__((ext_vector_type(8)));
typedef float  f32x4  __attribute__((ext_vector_type(4)));
typedef int    i32x4  __attribute__((ext_vector_type(4)));

__device__ __forceinline__ unsigned short f2bf_rn(float f) {
  unsigned int u = __float_as_uint(f);
  u += 0x7fffu + ((u >> 16) & 1u);          // round-to-nearest-even
  return (unsigned short)(u >> 16);
}
__device__ __forceinline__ float bf2f(unsigned short h) {
  return __uint_as_float(((unsigned int)h) << 16);
}

__device__ __forceinline__ f32x4 mfma16(bf16x8 a, bf16x8 b, f32x4 c) {
  return __builtin_amdgcn_mfma_f32_16x16x32_bf16(a, b, c, 0, 0, 0);
}

// coherent 16B load: bypasses L1/L2 (sc0 sc1), reads coherence point.
// NO waitcnt inside -- caller batches loads then drains once.
__device__ __forceinline__ bf16x8 coh_load16(const unsigned short* p) {
  bf16x8 r;
  asm volatile("global_load_dwordx4 %0, %1, off sc0 sc1"
               : "=v"(r) : "v"(p) : "memory");
  return r;
}

__device__ __forceinline__ i32x4 coh_load_flags(const int* p) {
  i32x4 r;
  asm volatile("global_load_dwordx4 %0, %1, off sc0 sc1"
               : "=v"(r) : "v"(p) : "memory");
  asm volatile("s_waitcnt vmcnt(0)" ::: "memory");
  return r;
}

// single-word coherent poll load (all lanes same address -> 1 request)
__device__ __forceinline__ int coh_load_word(const int* p) {
  int r;
  asm volatile("global_load_dword %0, %1, off sc0 sc1"
               : "=v"(r) : "v"(p) : "memory");
  asm volatile("s_waitcnt vmcnt(0)" ::: "memory");
  return r;
}

// x -> hi/lo bf16 split (Markidis) so drive GEMM is ~fp32-exact at MFMA speed.
__global__ void k_conv_x(const float* __restrict__ x,
                         unsigned short* __restrict__ xhi,
                         unsigned short* __restrict__ xlo, int n) {
  int i = blockIdx.x * blockDim.x + threadIdx.x;
  if (i < n) {
    float v = x[i];
    unsigned short h = f2bf_rn(v);
    xhi[i] = h;
    xlo[i] = f2bf_rn(v - bf2f(h));
  }
}

__global__ __launch_bounds__(NTHR, 1) void rnn_persist(
    const float* __restrict__ h0,      // [64][2048]
    const float* __restrict__ Wrec,    // [2048][2048]
    const float* __restrict__ Winp,    // [2048][128]
    const float* __restrict__ tonic,   // [2048]
    const int*   __restrict__ Wmask,   // [2048][2048]
    const int*   __restrict__ Wsign,   // [2048][2048]
    const unsigned short* __restrict__ xhi,  // [64][512][128] bf16
    const unsigned short* __restrict__ xlo,
    unsigned short* __restrict__ rbuf, // [2][64][2048] bf16 (double buffer)
    int* __restrict__ flags,           // [4][64] per-WG epoch flags, zeroed
    int* __restrict__ done,            // [4][32] group done words (128B apart)
    float* __restrict__ out)           // [64][512][2048]
{
  __shared__ unsigned short wlds[COLS][N_ + WPAD];   // 131584 B: W_eff slice bf16
  __shared__ unsigned short winph[COLS][I_ + IPAD];  // 8704 B
  __shared__ unsigned short winpl[COLS][I_ + IPAD];  // 8704 B
  __shared__ f32x4 red[3][2][64];                    // 6144 B: cross-wave K reduction

  const int wg   = blockIdx.x;
  const int g    = wg >> 2;        // n-block 0..63 (rank within group)
  const int q    = wg & 3;         // b-group 0..3 (sync domain)
  const int n0   = g * COLS;
  const int b0   = q * ROWS;
  const int tid  = threadIdx.x;
  const int wave = tid >> 6;
  const int lane = tid & 63;
  const int l15  = lane & 15;
  const int lhi  = lane >> 4;
  int* gflags = flags + q * GWG;   // this group's 64 epoch flags
  int* gdone  = done + q * 32;     // this group's done word (own 128B line)
  const bool is_agg = (g == 0);    // one aggregator WG per group

  // ---- prologue: W_eff = relu(Wrec) * mask * sign -> bf16 LDS slice
  for (int i = tid; i < COLS * N_; i += NTHR) {
    int rr = i >> 11;                 // local n row (0..31)
    int kk = i & (N_ - 1);
    size_t gi = (size_t)(n0 + rr) * N_ + kk;
    float w = Wrec[gi];
    w = w > 0.f ? w : 0.f;
    w *= (float)(Wmask[gi] * Wsign[gi]);
    wlds[rr][kk] = f2bf_rn(w);
  }
  // Winp slice -> hi/lo bf16 LDS
  for (int i = tid; i < COLS * I_; i += NTHR) {
    int rr = i >> 7;
    int kk = i & (I_ - 1);
    float w = Winp[(size_t)(n0 + rr) * I_ + kk];
    unsigned short hh = f2bf_rn(w);
    winph[rr][kk] = hh;
    winpl[rr][kk] = f2bf_rn(w - bf2f(hh));
  }

  // wave0 owns the h state for this tile, in C/D fragment layout:
  // col = lane&15 (n), row = (lane>>4)*4 + j (b).
  float hreg[2][4];
  float ton[2] = {0.f, 0.f};
  if (wave == 0) {
    #pragma unroll
    for (int f = 0; f < 2; ++f) {
      ton[f] = tonic[n0 + f * 16 + l15];
      #pragma unroll
      for (int j = 0; j < 4; ++j) {
        int b = b0 + lhi * 4 + j;
        int n = n0 + f * 16 + l15;
        float h = h0[(size_t)b * N_ + n];
        hreg[f][j] = h;
        float r = h > 0.f ? h : 0.f;
        __hip_atomic_store(&rbuf[(size_t)b * N_ + n], f2bf_rn(r),
                           __ATOMIC_RELAXED, __HIP_MEMORY_SCOPE_AGENT);
      }
    }
  }

  // ---- group sync, epoch 1 (hierarchical)
  __syncthreads();
  if (wave == 0) {
    asm volatile("s_waitcnt vmcnt(0)" ::: "memory");
    if (lane == 0)
      __hip_atomic_store(&gflags[g], 1, __ATOMIC_RELAXED, __HIP_MEMORY_SCOPE_AGENT);
    if (is_agg) {
      const int* fp = gflags + l15 * 4;
      for (;;) {
        i32x4 f = coh_load_flags(fp);
        bool ok = (f[0] >= 1) && (f[1] >= 1) && (f[2] >= 1) && (f[3] >= 1);
        if (__all(ok)) break;
        __builtin_amdgcn_s_sleep(1);
      }
      if (lane == 0)
        __hip_atomic_store(gdone, 1, __ATOMIC_RELAXED, __HIP_MEMORY_SCOPE_AGENT);
    } else {
      while (coh_load_word(gdone) < 1)
        __builtin_amdgcn_s_sleep(1);
    }
    asm volatile("" ::: "memory");
  }
  __syncthreads();

  const float a = 0.1f;
  const float oma = 1.0f - a;

  for (int t = 0; t < T_; ++t) {
    const unsigned short* rcur = rbuf + (size_t)(t & 1) * (B_ * N_);
    unsigned short*       rnxt = rbuf + (size_t)((t + 1) & 1) * (B_ * N_);

    f32x4 acc0 = {0.f, 0.f, 0.f, 0.f};
    f32x4 acc1 = {0.f, 0.f, 0.f, 0.f};

    // ---- recurrent GEMM, K split over 4 waves (512 each)
    // phase 1: issue all 16 coherent A-frag loads (16 outstanding)
    const int kq = wave * 512;
    const unsigned short* arow = rcur + (size_t)(b0 + l15) * N_;
    bf16x8 afr[16];
    #pragma unroll
    for (int ki = 0; ki < 16; ++ki) {
      afr[ki] = coh_load16(arow + kq + ki * 32 + lhi * 8);
    }
    // single drain + scheduling fence (rule #18), then consume
    asm volatile("s_waitcnt vmcnt(0)" ::: "memory");
    __builtin_amdgcn_sched_barrier(0);
    #pragma unroll
    for (int ki = 0; ki < 16; ++ki) {
      int k = kq + ki * 32 + lhi * 8;
      bf16x8 bf0 = *reinterpret_cast<const bf16x8*>(&wlds[l15][k]);      // W frag col 0..15
      bf16x8 bf1 = *reinterpret_cast<const bf16x8*>(&wlds[16 + l15][k]); // W frag col 16..31
      acc0 = mfma16(afr[ki], bf0, acc0);
      acc1 = mfma16(afr[ki], bf1, acc1);
    }

    // ---- fused input drive: x[:,t,:] @ Winp^T, 3-pass split-bf16, i-chunk per wave
    {
      int i0 = wave * 32 + lhi * 8;
      size_t xoff = ((size_t)(b0 + l15) * T_ + t) * I_ + i0;
      bf16x8 xh  = *reinterpret_cast<const bf16x8*>(xhi + xoff);
      bf16x8 xl  = *reinterpret_cast<const bf16x8*>(xlo + xoff);
      bf16x8 wh0 = *reinterpret_cast<const bf16x8*>(&winph[l15][i0]);
      bf16x8 wl0 = *reinterpret_cast<const bf16x8*>(&winpl[l15][i0]);
      bf16x8 wh1 = *reinterpret_cast<const bf16x8*>(&winph[16 + l15][i0]);
      bf16x8 wl1 = *reinterpret_cast<const bf16x8*>(&winpl[16 + l15][i0]);
      acc0 = mfma16(xh, wh0, acc0);
      acc0 = mfma16(xh, wl0, acc0);
      acc0 = mfma16(xl, wh0, acc0);
      acc1 = mfma16(xh, wh1, acc1);
      acc1 = mfma16(xh, wl1, acc1);
      acc1 = mfma16(xl, wh1, acc1);
    }

    // ---- cross-wave reduction (waves 1..3 -> LDS, wave 0 sums)
    if (wave != 0) {
      red[wave - 1][0][lane] = acc0;
      red[wave - 1][1][lane] = acc1;
    }
    __syncthreads();   // all waves' rcur reads complete past this point
    if (wave == 0) {
      #pragma unroll
      for (int w = 0; w < 3; ++w) {
        acc0 += red[w][0][lane];
        acc1 += red[w][1][lane];
      }
      float rvals[2][4];
      // h update + coherent rnxt stores (they gate the flag)
      #pragma unroll
      for (int f = 0; f < 2; ++f) {
        f32x4 accv = (f == 0) ? acc0 : acc1;
        int n = n0 + f * 16 + l15;
        #pragma unroll
        for (int j = 0; j < 4; ++j) {
          float s  = accv[j] + ton[f];
          float hn = oma * hreg[f][j] + a * s;
          hreg[f][j] = hn;
          float r = hn > 0.f ? hn : 0.f;
          rvals[f][j] = r;
          int b = b0 + lhi * 4 + j;
          __hip_atomic_store(&rnxt[(size_t)b * N_ + n], f2bf_rn(r),
                             __ATOMIC_RELAXED, __HIP_MEMORY_SCOPE_AGENT);
        }
      }
      // drain rnxt to coherence point, then publish epoch
      asm volatile("s_waitcnt vmcnt(0)" ::: "memory");
      const int epoch = t + 2;
      if (lane == 0)
        __hip_atomic_store(&gflags[g], epoch, __ATOMIC_RELAXED, __HIP_MEMORY_SCOPE_AGENT);
      if (is_agg) {
        // aggregator: poll the 64 per-WG flags (only 4 WGs chip-wide do this)
        const int* fp = gflags + l15 * 4;
        for (;;) {
          i32x4 f = coh_load_flags(fp);
          bool ok = (f[0] >= epoch) && (f[1] >= epoch) &&
                    (f[2] >= epoch) && (f[3] >= epoch);
          if (__all(ok)) break;
          __builtin_amdgcn_s_sleep(1);
        }
        if (lane == 0)
          __hip_atomic_store(gdone, epoch, __ATOMIC_RELAXED, __HIP_MEMORY_SCOPE_AGENT);
      } else {
        // consumers: poll ONE word, all lanes same address (1 request/iter)
        while (coh_load_word(gdone) < epoch)
          __builtin_amdgcn_s_sleep(1);
      }
      asm volatile("" ::: "memory");   // no rnxt-data load may be hoisted above
      // out stores AFTER poll: drain overlaps next step's A-load RTT
      #pragma unroll
      for (int f = 0; f < 2; ++f) {
        int n = n0 + f * 16 + l15;
        #pragma unroll
        for (int j = 0; j < 4; ++j) {
          int b = b0 + lhi * 4 + j;
          out[((size_t)b * T_ + t) * N_ + n] = rvals[f][j];
        }
      }
    }
    __syncthreads();
  }
}

extern "C" void kernel_launch(void* const* d_in, const int* in_sizes, int n_in,
                              void* d_out, int out_size, void* d_ws, size_t ws_size,
                              hipStream_t stream) {
  (void)in_sizes; (void)n_in; (void)out_size; (void)ws_size;
  const float* x     = (const float*)d_in[0];
  const float* h0    = (const float*)d_in[1];
  const float* Wrec  = (const float*)d_in[2];
  const float* Winp  = (const float*)d_in[3];
  const float* tonic = (const float*)d_in[4];
  const int*   Wmask = (const int*)d_in[5];
  const int*   Wsign = (const int*)d_in[6];
  float* out = (float*)d_out;

  char* ws = (char*)d_ws;
  const size_t nx = (size_t)B_ * T_ * I_;          // 4,194,304
  size_t off = 0;
  unsigned short* xhi = (unsigned short*)(ws + off); off += nx * 2;
  unsigned short* xlo = (unsigned short*)(ws + off); off += nx * 2;
  unsigned short* rbuf = (unsigned short*)(ws + off); off += (size_t)2 * B_ * N_ * 2;
  off = (off + 255) & ~(size_t)255;
  int* flags = (int*)(ws + off);                   // [4][64] epochs
  int* done  = flags + 4 * GWG;                    // [4][32] done words

  hipMemsetAsync(flags, 0, (4 * GWG + 4 * 32) * sizeof(int), stream);

  int cthr = 256;
  int cblk = (int)((nx + cthr - 1) / cthr);
  k_conv_x<<<cblk, cthr, 0, stream>>>(x, xhi, xlo, (int)nx);

  rnn_persist<<<NWG, NTHR, 0, stream>>>(h0, Wrec, Winp, tonic, Wmask, Wsign,
                                        xhi, xlo, rbuf, flags, done, out);
}